// Round 1
// baseline (502.817 us; speedup 1.0000x reference)
//
#include <hip/hip_runtime.h>

#define NN 4096
#define HH 32
#define DD 128
#define MM 16
#define PP 8192

__device__ __forceinline__ float dot4f(float4 a, float4 b) {
  return a.x * b.x + a.y * b.y + a.z * b.z + a.w * b.w;
}

// ---------------------------------------------------------------- K1: RMS inv
__global__ void k1_rms(const float* __restrict__ X, float* __restrict__ inv) {
  const int m = blockIdx.x;
  const int tid = threadIdx.x;
  float s = 0.f;
#pragma unroll
  for (int i = 0; i < 16; ++i) {
    float v = X[(size_t)m * NN + i * 256 + tid];
    s += v * v;
  }
#pragma unroll
  for (int off = 1; off < 64; off <<= 1) s += __shfl_xor(s, off, 64);
  __shared__ float red[4];
  if ((tid & 63) == 0) red[tid >> 6] = s;
  __syncthreads();
  if (tid == 0) {
    float t = red[0] + red[1] + red[2] + red[3];
    inv[m] = rsqrtf(t * (1.0f / (float)NN));
  }
}

// ------------------------------------------------- K2a: QKV quarter partials
// grid 768 = 3 mats x 4 k-quarters x 64 row-groups. block 256 (4 waves).
// wave covers k-slice of 256 within its quarter; lane=(m4,g): 4 m's x 16 k.
// X lives in registers (read once per wave); W streamed, read exactly once.
__global__ __launch_bounds__(256, 4) void k2_qkv(
    const float* __restrict__ X, const float* __restrict__ Wq,
    const float* __restrict__ Wk, const float* __restrict__ Wv,
    float* __restrict__ c_part) {
  __shared__ float lds_c[4][64][18];  // [wave][j_local][m], stride 18 anti-conflict
  const int b = blockIdx.x;
  const int mat = b >> 8;
  const int rem = b & 255;
  const int qt = rem >> 6;
  const int jg = rem & 63;
  const float* W = (mat == 0) ? Wq : (mat == 1) ? Wk : Wv;
  const int tid = threadIdx.x;
  const int wave = tid >> 6;
  const int lane = tid & 63;
  const int m4 = lane & 3;
  const int g = lane >> 2;
  const int kbase = qt * 1024 + wave * 256 + g * 16;

  float4 xr[4][4];  // [mi][j4]; m = mi*4 + m4
#pragma unroll
  for (int mi = 0; mi < 4; ++mi) {
    const float* xp = X + (size_t)(mi * 4 + m4) * NN + kbase;
#pragma unroll
    for (int j = 0; j < 4; ++j) xr[mi][j] = *(const float4*)(xp + j * 4);
  }

  const int j0 = jg * 64;
  for (int grp = 0; grp < 16; ++grp) {
    float acc[4][4];  // [row r][mi]
#pragma unroll
    for (int r = 0; r < 4; ++r)
#pragma unroll
      for (int mi = 0; mi < 4; ++mi) acc[r][mi] = 0.f;
#pragma unroll
    for (int r = 0; r < 4; ++r) {
      const float* wp = W + (size_t)(j0 + grp * 4 + r) * NN + kbase;
      float4 w0 = *(const float4*)(wp);
      float4 w1 = *(const float4*)(wp + 4);
      float4 w2 = *(const float4*)(wp + 8);
      float4 w3 = *(const float4*)(wp + 12);
#pragma unroll
      for (int mi = 0; mi < 4; ++mi)
        acc[r][mi] = acc[r][mi] + dot4f(xr[mi][0], w0) + dot4f(xr[mi][1], w1) +
                     dot4f(xr[mi][2], w2) + dot4f(xr[mi][3], w3);
    }
    // butterfly reduce over g (lane bits 2..5)
#pragma unroll
    for (int off = 4; off < 64; off <<= 1)
#pragma unroll
      for (int r = 0; r < 4; ++r)
#pragma unroll
        for (int mi = 0; mi < 4; ++mi)
          acc[r][mi] += __shfl_xor(acc[r][mi], off, 64);
    if (g == 0) {
#pragma unroll
      for (int r = 0; r < 4; ++r)
#pragma unroll
        for (int mi = 0; mi < 4; ++mi)
          lds_c[wave][grp * 4 + r][mi * 4 + m4] = acc[r][mi];
    }
  }
  __syncthreads();
  // combine 4 waves' k-slices -> quarter partial, store [mat][qt][m][4096]
#pragma unroll
  for (int i = 0; i < 4; ++i) {
    const int m = i * 4 + (tid >> 6);
    const int j = tid & 63;
    float s = lds_c[0][j][m] + lds_c[1][j][m] + lds_c[2][j][m] + lds_c[3][j][m];
    c_part[(((size_t)(mat * 4 + qt) * 16 + m) << 12) + (j0 + j)] = s;
  }
}

// --------------------------------------- K2b: combine quarters, scale by inv
// qkv[mat][h][m][d] = inv[m] * sum_qt c_part[mat][qt][m][h*128+d]
__global__ void k2b_combine(const float* __restrict__ c_part,
                            const float* __restrict__ inv,
                            float* __restrict__ qkv) {
  const int t = blockIdx.x * 256 + threadIdx.x;  // 0..196607
  const int mat = t >> 16;
  const int r = t & 65535;
  const int h = r >> 11;
  const int m = (r >> 7) & 15;
  const int d = r & 127;
  const int j = h * 128 + d;
  float s = 0.f;
#pragma unroll
  for (int qt = 0; qt < 4; ++qt)
    s += c_part[(((size_t)(mat * 4 + qt) * 16 + m) << 12) + j];
  qkv[t] = s * inv[m];
}

// ------------------------------------------------- K3: attention partials
// grid (33, 32): chunk 0..31 = 256 cached positions; chunk 32 = 16 appended.
// block 256 = 4 waves; tile 32 p staged via LDS; lane=(m4,g16): 4 m x 8 d.
__global__ __launch_bounds__(256, 4) void k3_attn(
    const float* __restrict__ cK, const float* __restrict__ cV,
    const float* __restrict__ qkv, float* __restrict__ o_part,
    float* __restrict__ denom_part) {
  __shared__ float smem[8192];  // 32 KB: K tile [0:4096], V tile [4096:8192]
  __shared__ float dlds[4][16];
  const int chunk = blockIdx.x;
  const int h = blockIdx.y;
  const int tid = threadIdx.x;
  const int wave = tid >> 6;
  const int lane = tid & 63;
  const int m4 = lane & 3;
  const int g = lane >> 2;
  const int d0 = g * 8;

  float4 qr[4][2];
  {
    const float* qf = qkv + (size_t)h * 2048;
#pragma unroll
    for (int mi = 0; mi < 4; ++mi) {
      const float* qp = qf + (mi * 4 + m4) * 128 + d0;
      qr[mi][0] = *(const float4*)(qp);
      qr[mi][1] = *(const float4*)(qp + 4);
    }
  }
  float oacc[4][8];
#pragma unroll
  for (int mi = 0; mi < 4; ++mi)
#pragma unroll
    for (int j = 0; j < 8; ++j) oacc[mi][j] = 0.f;
  float den[4] = {0.f, 0.f, 0.f, 0.f};

  const float* Ksrc;
  const float* Vsrc;
  int np;
  if (chunk < 32) {
    Ksrc = cK + ((size_t)h * PP + chunk * 256) * DD;
    Vsrc = cV + ((size_t)h * PP + chunk * 256) * DD;
    np = 256;
  } else {
    Ksrc = qkv + 65536 + (size_t)h * 2048;   // appended k rows [16][128]
    Vsrc = qkv + 131072 + (size_t)h * 2048;  // appended v rows
    np = 16;
  }

  for (int t0 = 0; t0 < np; t0 += 32) {
    const int rows = (np - t0 < 32) ? (np - t0) : 32;
    const int nf4 = rows * 32;
    const float4* gk = (const float4*)(Ksrc + (size_t)t0 * DD);
    const float4* gv = (const float4*)(Vsrc + (size_t)t0 * DD);
    for (int s = tid; s < nf4; s += 256) {
      ((float4*)smem)[s] = gk[s];
      ((float4*)(smem + 4096))[s] = gv[s];
    }
    __syncthreads();
    const int per = rows >> 2;  // 8 (or 4 on appended chunk)
#pragma unroll 4
    for (int pi = 0; pi < per; ++pi) {
      const int p = wave * per + pi;
      const float* kp = smem + p * DD + d0;
      float4 ka = *(const float4*)(kp);
      float4 kb = *(const float4*)(kp + 4);
      float c[4];
#pragma unroll
      for (int mi = 0; mi < 4; ++mi)
        c[mi] = dot4f(qr[mi][0], ka) + dot4f(qr[mi][1], kb);
#pragma unroll
      for (int off = 4; off < 64; off <<= 1)
#pragma unroll
        for (int mi = 0; mi < 4; ++mi) c[mi] += __shfl_xor(c[mi], off, 64);
      const float* vp = smem + 4096 + p * DD + d0;
      float4 va = *(const float4*)(vp);
      float4 vb = *(const float4*)(vp + 4);
#pragma unroll
      for (int mi = 0; mi < 4; ++mi) {
        float e = __expf(c[mi]);
        den[mi] += e;
        oacc[mi][0] += e * va.x;
        oacc[mi][1] += e * va.y;
        oacc[mi][2] += e * va.z;
        oacc[mi][3] += e * va.w;
        oacc[mi][4] += e * vb.x;
        oacc[mi][5] += e * vb.y;
        oacc[mi][6] += e * vb.z;
        oacc[mi][7] += e * vb.w;
      }
    }
    __syncthreads();
  }
  // dump per-wave o partials into smem (staging buffers are free now)
#pragma unroll
  for (int mi = 0; mi < 4; ++mi) {
    float* op = smem + wave * 2048 + (mi * 4 + m4) * 128 + d0;
    *(float4*)(op) = make_float4(oacc[mi][0], oacc[mi][1], oacc[mi][2], oacc[mi][3]);
    *(float4*)(op + 4) = make_float4(oacc[mi][4], oacc[mi][5], oacc[mi][6], oacc[mi][7]);
  }
  if (g == 0) {
#pragma unroll
    for (int mi = 0; mi < 4; ++mi) dlds[wave][mi * 4 + m4] = den[mi];
  }
  __syncthreads();
  const size_t ob = ((size_t)h * 33 + chunk) * 2048;
#pragma unroll
  for (int i = 0; i < 8; ++i) {
    const int md = i * 256 + tid;
    o_part[ob + md] = smem[md] + smem[2048 + md] + smem[4096 + md] + smem[6144 + md];
  }
  if (tid < 16)
    denom_part[((size_t)h * 33 + chunk) * 16 + tid] =
        dlds[0][tid] + dlds[1][tid] + dlds[2][tid] + dlds[3][tid];
}

// -------------------------------------------------------- K4: final reduce
__global__ void k4_final(const float* __restrict__ o_part,
                         const float* __restrict__ denom_part,
                         float* __restrict__ out) {
  const int h = blockIdx.x;
  const int tid = threadIdx.x;
  __shared__ float dinv[16];
  if (tid < 16) {
    float s = 0.f;
    for (int c = 0; c < 33; ++c) s += denom_part[((size_t)h * 33 + c) * 16 + tid];
    dinv[tid] = 1.0f / s;
  }
  __syncthreads();
#pragma unroll
  for (int i = 0; i < 8; ++i) {
    const int md = i * 256 + tid;
    float s = 0.f;
    for (int c = 0; c < 33; ++c) s += o_part[((size_t)h * 33 + c) * 2048 + md];
    const int m = md >> 7;
    const int d = md & 127;
    out[(size_t)m * NN + h * DD + d] = s * dinv[m];
  }
}

extern "C" void kernel_launch(void* const* d_in, const int* in_sizes, int n_in,
                              void* d_out, int out_size, void* d_ws, size_t ws_size,
                              hipStream_t stream) {
  (void)in_sizes; (void)n_in; (void)out_size; (void)ws_size;
  const float* X  = (const float*)d_in[0];
  const float* Wq = (const float*)d_in[1];
  const float* Wk = (const float*)d_in[2];
  const float* Wv = (const float*)d_in[3];
  const float* cK = (const float*)d_in[4];
  const float* cV = (const float*)d_in[5];
  float* out = (float*)d_out;
  float* ws = (float*)d_ws;

  float* inv        = ws;                       // 16
  float* c_part     = ws + 16;                  // 3*4*16*4096 = 786432
  float* qkv        = c_part + 786432;          // 3*32*16*128 = 196608
  float* o_part     = qkv + 196608;             // 32*33*16*128 = 2162688
  float* denom_part = o_part + 2162688;         // 32*33*16 = 16896

  k1_rms<<<16, 256, 0, stream>>>(X, inv);
  k2_qkv<<<768, 256, 0, stream>>>(X, Wq, Wk, Wv, c_part);
  k2b_combine<<<768, 256, 0, stream>>>(c_part, inv, qkv);
  k3_attn<<<dim3(33, 32), 256, 0, stream>>>(cK, cV, qkv, o_part, denom_part);
  k4_final<<<32, 256, 0, stream>>>(o_part, denom_part, out);
}